// Round 3
// baseline (351.323 us; speedup 1.0000x reference)
//
#include <hip/hip_runtime.h>

#define KK 32
#define KP 33
#define NMAXC 256
#define BCH 32            // bsz * ENS
#define NPADC 32768
#define TARGETC 32640
#define LSEG 64           // items per segment
#define MSEG 512          // NPADC / LSEG
#define GSZ 32            // segments per group
#define NG 16             // MSEG / GSZ
#define SS 2

#define OFFS(i) ((i)*255 - (i)*((i)-1)/2)

// 33-point truncated polynomial product via rotate-by-1 (DPP-friendly).
__device__ __forceinline__ double conv33(double a, double b) {
    int lane = threadIdx.x & 63;
    double s0 = 0.0, s1 = 0.0;
    double brot = b;
#pragma unroll
    for (int j = 0; j < KP; ++j) {
        double aj = __shfl(a, j, 64);
        double m = (j <= lane) ? aj : 0.0;
        if (j & 1) s1 = fma(m, brot, s1); else s0 = fma(m, brot, s0);
        brot = __shfl_up(brot, 1, 64);
    }
    return s0 + s1;
}

// ---- kernel 1: row-based x = exp(theta); coalesced X writes, no decode_ij
__global__ void k_exp_row(const float* __restrict__ sc, double* __restrict__ X) {
    int i = blockIdx.x, b = blockIdx.y, j = threadIdx.x;
    if (j <= i) return;
    int t = OFFS(i) + j - i - 1;
    double th = (double)sc[((size_t)b * NMAXC + i) * NMAXC + j] +
                (double)sc[((size_t)b * NMAXC + j) * NMAXC + i];
    X[(size_t)b * NPADC + t] = exp(th);
}

__global__ void k_padX(double* __restrict__ X) {
    int idx = blockIdx.x * 256 + threadIdx.x;     // 4096
    int b = idx >> 7, p = idx & 127;
    X[(size_t)b * NPADC + TARGETC + p] = 0.0;
}

// ---- kernel 1b: transpose+widen U: UT[s][b][t] = (double)U[s][t][b]
__global__ void k_utrans(const float* __restrict__ U, double* __restrict__ UT) {
    __shared__ float tile[64][33];
    int s = blockIdx.y;
    int t0 = blockIdx.x * 64;
    int tid = threadIdx.x;                        // 256
#pragma unroll
    for (int it = 0; it < 8; ++it) {
        int tr = it * 8 + (tid >> 5);
        int b = tid & 31;
        tile[tr][b] = U[((size_t)s * NPADC + t0 + tr) * BCH + b];
    }
    __syncthreads();
#pragma unroll
    for (int it = 0; it < 8; ++it) {
        int b = it * 4 + (tid >> 6);
        int t = tid & 63;
        UT[((size_t)s * BCH + b) * NPADC + t0 + t] = (double)tile[t][b];
    }
}

// ---- kernel 2: per-segment elementary symmetric polys (4 segments / block)
__global__ void k_block_poly(const double* __restrict__ X, double* __restrict__ Bp) {
    int lane = threadIdx.x & 63;
    int blk = blockIdx.x * 4 + (threadIdx.x >> 6);   // b*MSEG + m
    int b = blk >> 9, m = blk & (MSEG - 1);
    double xa = X[(size_t)b * NPADC + (size_t)m * LSEG + lane];
    double c = (lane == 0) ? 1.0 : 0.0;
#pragma unroll
    for (int j = 0; j < LSEG; ++j) {
        double xj = __shfl(xa, j, 64);
        double up = __shfl_up(c, 1, 64);
        if (lane == 0) up = 0.0;
        c = fma(xj, up, c);
    }
    if (lane < KP) Bp[(size_t)blk * KP + lane] = c;
}

// ---- kernel 3a: suffix-inclusive within group + group polys (4 groups / block)
__global__ void k_group_partial(const double* __restrict__ Bp,
                                double* __restrict__ sfxI, double* __restrict__ gpoly) {
    int lane = threadIdx.x & 63;
    int blk = blockIdx.x * 4 + (threadIdx.x >> 6);   // b*NG + g
    int b = blk / NG, g = blk % NG;
    double run = (lane == 0) ? 1.0 : 0.0;
    for (int i = GSZ - 1; i >= 0; --i) {
        int m = g * GSZ + i;
        double bp = (lane < KP) ? Bp[((size_t)b * MSEG + m) * KP + lane] : 0.0;
        run = conv33(bp, run);
        if (lane < KP) sfxI[((size_t)b * MSEG + m) * KP + lane] = run;
    }
    if (lane < KP) gpoly[(size_t)blk * KP + lane] = run;
}

// ---- kernel 3b: suffix scan over group polys (exclusive carries)
__global__ void k_group_scan(const double* __restrict__ gpoly, double* __restrict__ gcarry) {
    int lane = threadIdx.x;
    int b = blockIdx.x;
    double run = (lane == 0) ? 1.0 : 0.0;
    for (int g = NG - 1; g >= 0; --g) {
        if (lane < KP) gcarry[((size_t)b * NG + g) * KP + lane] = run;
        double gp = (lane < KP) ? gpoly[((size_t)b * NG + g) * KP + lane] : 0.0;
        run = conv33(gp, run);
    }
}

// ---- kernel 3c: per-segment suffix checkpoints (4 segments / block)
__global__ void k_checkpoints(const double* __restrict__ sfxI, const double* __restrict__ gcarry,
                              double* __restrict__ Cc) {
    int lane = threadIdx.x & 63;
    int blk = blockIdx.x * 4 + (threadIdx.x >> 6);   // b*MSEG + m
    int b = blk >> 9, m = blk & (MSEG - 1);
    double a = (lane < KP) ? sfxI[(size_t)blk * KP + lane] : 0.0;
    double cg = (lane < KP) ? gcarry[((size_t)b * NG + m / GSZ) * KP + lane] : 0.0;
    double out = conv33(a, cg);
    if (lane < KP) Cc[((size_t)b * (MSEG + 1) + m) * KP + lane] = out;
    if (m == 0 && lane < KP)
        Cc[((size_t)b * (MSEG + 1) + MSEG) * KP + lane] = (lane == 0) ? 1.0 : 0.0;
}

// ---- kernel 4: backward sfx sweep fused with sampling (4 segments / block)
__global__ void k_backward(const double* __restrict__ X, const double* __restrict__ Cc,
                           const double* __restrict__ UT,
                           unsigned long long* __restrict__ masks, int* __restrict__ tab) {
    int lane = threadIdx.x & 63;
    int blk = blockIdx.x * 4 + (threadIdx.x >> 6);   // b*MSEG + m
    int b = blk >> 9, m = blk & (MSEG - 1);
    double xa = X[(size_t)b * NPADC + (size_t)m * LSEG + lane];
    double u0 = UT[((size_t)0 * BCH + b) * NPADC + (size_t)m * LSEG + lane];
    double u1 = UT[((size_t)1 * BCH + b) * NPADC + (size_t)m * LSEG + lane];
    double c = (lane < KP) ? Cc[((size_t)b * (MSEG + 1) + m + 1) * KP + lane] : 0.0;
    int S0 = lane, S1 = lane;
    unsigned long long mk0 = 0, mk1 = 0;
#pragma unroll
    for (int j = LSEG - 1; j >= 0; --j) {
        double xj = __shfl(xa, j, 64);
        double up = __shfl_up(c, 1, 64);
        if (lane == 0) up = 0.0;
        double rhs = xj * up;                       // x_j * sfx[j+1][lane-1]
        double cn = fma(xj, up, c);                 // sfx[j][lane]
        double ud0 = __shfl(u0, j, 64);
        double ud1 = __shfl(u1, j, 64);
        bool i0 = (ud0 * cn < rhs);                 // lane0: rhs==0 -> false
        bool i1 = (ud1 * cn < rhs);
        unsigned long long b0 = __ballot(i0);
        unsigned long long b1 = __ballot(i1);
        if (lane == j) { mk0 = b0; mk1 = b1; }
        int t0 = __shfl_up(S0, 1, 64);
        int t1 = __shfl_up(S1, 1, 64);
        if (i0) S0 = t0;
        if (i1) S1 = t1;
        c = cn;
    }
    masks[((size_t)(0 * BCH + b) * MSEG + m) * LSEG + lane] = mk0;
    masks[((size_t)(1 * BCH + b) * MSEG + m) * LSEG + lane] = mk1;
    if (lane < KP) {
        tab[((size_t)(0 * BCH + b) * MSEG + m) * KP + lane] = S0;
        tab[((size_t)(1 * BCH + b) * MSEG + m) * KP + lane] = S1;
    }
}

// ---- kernel 5: hierarchical compose of per-segment tables -> per-segment entry states
__global__ void k_compose(const int* __restrict__ tab, int* __restrict__ rent) {
    __shared__ int tl[MSEG * KP];         // 67.6 KB
    __shared__ int gtab[16 * KP];
    __shared__ int gent[16];
    int sb = blockIdx.x;                  // s*BCH + b
    int tid = threadIdx.x;                // 1024
    const int* src = tab + (size_t)sb * MSEG * KP;
    for (int i = tid; i < MSEG * KP; i += 1024) tl[i] = src[i];
    __syncthreads();
    int w = tid >> 6, lane = tid & 63;
    int T = lane;
    for (int i = 0; i < 32; ++i) {
        int seg = w * 32 + i;
        int tv = (lane < KP) ? tl[seg * KP + lane] : 0;
        T = __shfl(tv, T, 64);
    }
    if (lane < KP) gtab[w * KP + lane] = T;
    __syncthreads();
    if (tid == 0) {
        int r = KK;
        for (int g = 0; g < 16; ++g) { gent[g] = r; r = gtab[g * KP + r]; }
    }
    __syncthreads();
    int r = gent[w];
    for (int i = 0; i < 32; ++i) {
        int seg = w * 32 + i;
        if (lane == 0) rent[(size_t)sb * MSEG + seg] = r;
        r = tl[seg * KP + r];
    }
}

// ---- kernel 6a: replay masks along realized path -> packed bitset (4 segments / block)
__global__ void k_replay(const unsigned long long* __restrict__ masks,
                         const int* __restrict__ rent, unsigned long long* __restrict__ bitflat) {
    int lane = threadIdx.x & 63;
    int blk = blockIdx.x * 4 + (threadIdx.x >> 6);   // sb*MSEG + m
    int sb = blk >> 9, m = blk & (MSEG - 1);
    unsigned long long mv = masks[(size_t)blk * LSEG + lane];
    unsigned mlo = (unsigned)mv, mhi = (unsigned)(mv >> 32);
    int r = rent[(size_t)sb * MSEG + m];             // wave-uniform
    int mybit = 0;
#pragma unroll
    for (int j = 0; j < LSEG; ++j) {
        unsigned l = __shfl(mlo, j, 64);
        unsigned h = __shfl(mhi, j, 64);
        unsigned long long mj = ((unsigned long long)h << 32) | l;
        int inc = (int)((mj >> r) & 1ull);
        if (lane == j) mybit = inc;
        r -= inc;
    }
    unsigned long long packed = __ballot(mybit != 0);
    if (lane == 0) bitflat[blk] = packed;
}

// ---- kernel 6b: coalesced symmetric mask emission from LDS bitset
__global__ void k_emit_mask(const unsigned long long* __restrict__ bitflat,
                            float* __restrict__ outMask) {
    __shared__ unsigned long long bf[MSEG];
    int sb = blockIdx.y;
    int i = blockIdx.x;
    int j = threadIdx.x;                  // 256
    bf[j] = bitflat[(size_t)sb * MSEG + j];
    bf[j + 256] = bitflat[(size_t)sb * MSEG + 256 + j];
    __syncthreads();
    float v = 0.0f;
    if (j > i) {
        int t = OFFS(i) + j - i - 1;
        v = (float)((bf[t >> 6] >> (t & 63)) & 1ull);
    } else if (j < i) {
        int t = OFFS(j) + i - j - 1;
        v = (float)((bf[t >> 6] >> (t & 63)) & 1ull);
    }
    outMask[((size_t)sb * NMAXC + i) * NMAXC + j] = v;
}

// ---- kernel 7a: flat marginals by deflation (coalesced)
__global__ void k_margflat(const double* __restrict__ X, const double* __restrict__ Cc,
                           float* __restrict__ margflat) {
    __shared__ double e[KP];
    int b = blockIdx.y;
    int t = blockIdx.x * 256 + threadIdx.x;
    if (threadIdx.x < KP) e[threadIdx.x] = Cc[(size_t)b * (MSEG + 1) * KP + threadIdx.x];
    __syncthreads();
    double x = X[(size_t)b * NPADC + t];
    double f = 1.0;
#pragma unroll
    for (int k = 1; k < KK; ++k) f = fma(-x, f, e[k]);
    margflat[(size_t)b * NPADC + t] = (float)(x * f / e[KK]);
}

// ---- kernel 7b: coalesced symmetric marginal emission (lower-tri gathers hit L2)
__global__ void k_emit_marg(const float* __restrict__ margflat, float* __restrict__ outMarg) {
    int b = blockIdx.y;
    int i = blockIdx.x;
    int j = threadIdx.x;                  // 256
    float v = 0.0f;
    if (j > i) v = margflat[(size_t)b * NPADC + OFFS(i) + j - i - 1];
    else if (j < i) v = margflat[(size_t)b * NPADC + OFFS(j) + i - j - 1];
    outMarg[((size_t)b * NMAXC + i) * NMAXC + j] = v;
}

extern "C" void kernel_launch(void* const* d_in, const int* in_sizes, int n_in,
                              void* d_out, int out_size, void* d_ws, size_t ws_size,
                              hipStream_t stream) {
    const float* scores = (const float*)d_in[0];
    const float* uniforms = (const float*)d_in[1];

    char* ws = (char*)d_ws;
    size_t off = 0;
    auto alloc = [&](size_t bytes) {
        void* p = ws + off;
        off += (bytes + 255) & ~(size_t)255;
        return p;
    };
    double* X      = (double*)alloc((size_t)BCH * NPADC * 8);
    double* UT     = (double*)alloc((size_t)SS * BCH * NPADC * 8);
    double* Bp     = (double*)alloc((size_t)BCH * MSEG * KP * 8);
    double* sfxI   = (double*)alloc((size_t)BCH * MSEG * KP * 8);
    double* gpoly  = (double*)alloc((size_t)BCH * NG * KP * 8);
    double* gcarry = (double*)alloc((size_t)BCH * NG * KP * 8);
    double* Cc     = (double*)alloc((size_t)BCH * (MSEG + 1) * KP * 8);
    unsigned long long* masks = (unsigned long long*)alloc((size_t)SS * BCH * MSEG * LSEG * 8);
    int* tab       = (int*)alloc((size_t)SS * BCH * MSEG * KP * 4);
    int* rent      = (int*)alloc((size_t)SS * BCH * MSEG * 4);
    unsigned long long* bitflat = (unsigned long long*)alloc((size_t)SS * BCH * MSEG * 8);
    float* margflat = (float*)alloc((size_t)BCH * NPADC * 4);
    if (off > ws_size) return;            // ~62 MB

    k_exp_row<<<dim3(NMAXC, BCH), 256, 0, stream>>>(scores, X);
    k_padX<<<16, 256, 0, stream>>>(X);
    k_utrans<<<dim3(NPADC / 64, SS), 256, 0, stream>>>(uniforms, UT);
    k_block_poly<<<BCH * MSEG / 4, 256, 0, stream>>>(X, Bp);
    k_group_partial<<<BCH * NG / 4, 256, 0, stream>>>(Bp, sfxI, gpoly);
    k_group_scan<<<BCH, 64, 0, stream>>>(gpoly, gcarry);
    k_checkpoints<<<BCH * MSEG / 4, 256, 0, stream>>>(sfxI, gcarry, Cc);
    k_backward<<<BCH * MSEG / 4, 256, 0, stream>>>(X, Cc, UT, masks, tab);
    k_compose<<<SS * BCH, 1024, 0, stream>>>(tab, rent);
    k_replay<<<SS * BCH * MSEG / 4, 256, 0, stream>>>(masks, rent, bitflat);
    k_emit_mask<<<dim3(NMAXC, SS * BCH), 256, 0, stream>>>(bitflat, (float*)d_out);
    k_margflat<<<dim3(NPADC / 256, BCH), 256, 0, stream>>>(X, Cc, margflat);
    k_emit_marg<<<dim3(NMAXC, BCH), 256, 0, stream>>>(
        margflat, (float*)d_out + (size_t)SS * BCH * NMAXC * NMAXC);
}

// Round 5
// 182.258 us; speedup vs baseline: 1.9276x; 1.9276x over previous
//
#include <hip/hip_runtime.h>

#define KK 32
#define KP 33
#define NMAXC 256
#define BCH 32            // bsz * ENS
#define NPADC 32768
#define TARGETC 32640
#define LSEG 64           // items per segment
#define MSEG 512          // NPADC / LSEG
#define GSZ 32            // segments per group
#define NG 16             // MSEG / GSZ
#define SS 2

#define OFFS(i) ((i)*255 - (i)*((i)-1)/2)

// ---- cross-lane helpers on the VALU pipe (no ds_bpermute) ----
__device__ __forceinline__ int dpp_shr1_i(int v) {
    // wave_shr:1 (0x138), bound_ctrl=1 -> lane 0 receives 0
    return __builtin_amdgcn_mov_dpp(v, 0x138, 0xf, 0xf, true);
}
__device__ __forceinline__ double dpp_shr1_d(double v) {
    union { double d; int i[2]; } u; u.d = v;
    u.i[0] = dpp_shr1_i(u.i[0]);
    u.i[1] = dpp_shr1_i(u.i[1]);
    return u.d;
}
__device__ __forceinline__ double readlane_d(double v, int l) {
    union { double d; int i[2]; } u; u.d = v;
    union { double d; int i[2]; } r;
    r.i[0] = __builtin_amdgcn_readlane(u.i[0], l);
    r.i[1] = __builtin_amdgcn_readlane(u.i[1], l);
    return r.d;
}
__device__ __forceinline__ double readlane_f_to_d(float v, int l) {
    union { float f; int i; } u; u.f = v;
    union { float f; int i; } r;
    r.i = __builtin_amdgcn_readlane(u.i, l);
    return (double)r.f;
}

// 33-point truncated polynomial product; DPP zero-fill replaces the lane mask.
__device__ __forceinline__ double conv33(double a, double b) {
    double s0 = 0.0, s1 = 0.0;
    double brot = b;
#pragma unroll
    for (int j = 0; j < KP; ++j) {
        double aj = readlane_d(a, j);
        if (j & 1) s1 = fma(aj, brot, s1); else s0 = fma(aj, brot, s0);
        brot = dpp_shr1_d(brot);
    }
    return s0 + s1;
}

// ---- kernel 1: row-based x = exp(theta); coalesced X writes
__global__ void k_exp_row(const float* __restrict__ sc, double* __restrict__ X) {
    int i = blockIdx.x, b = blockIdx.y, j = threadIdx.x;
    if (j <= i) return;
    int t = OFFS(i) + j - i - 1;
    double th = (double)sc[((size_t)b * NMAXC + i) * NMAXC + j] +
                (double)sc[((size_t)b * NMAXC + j) * NMAXC + i];
    X[(size_t)b * NPADC + t] = exp(th);
}

__global__ void k_padX(double* __restrict__ X) {
    int idx = blockIdx.x * 256 + threadIdx.x;     // 4096
    int b = idx >> 7, p = idx & 127;
    X[(size_t)b * NPADC + TARGETC + p] = 0.0;
}

// ---- kernel 1b: transpose U (keep f32): UT[s][b][t] = U[s][t][b]
__global__ void k_utrans(const float* __restrict__ U, float* __restrict__ UT) {
    __shared__ float tile[64][33];
    int s = blockIdx.y;
    int t0 = blockIdx.x * 64;
    int tid = threadIdx.x;                        // 256
#pragma unroll
    for (int it = 0; it < 8; ++it) {
        int tr = it * 8 + (tid >> 5);
        int b = tid & 31;
        tile[tr][b] = U[((size_t)s * NPADC + t0 + tr) * BCH + b];
    }
    __syncthreads();
#pragma unroll
    for (int it = 0; it < 8; ++it) {
        int b = it * 4 + (tid >> 6);
        int t = tid & 63;
        UT[((size_t)s * BCH + b) * NPADC + t0 + t] = tile[t][b];
    }
}

// ---- kernel 2: per-segment elementary symmetric polys (4 segments / block)
__global__ void k_block_poly(const double* __restrict__ X, double* __restrict__ Bp) {
    int lane = threadIdx.x & 63;
    int blk = blockIdx.x * 4 + (threadIdx.x >> 6);   // b*MSEG + m
    int b = blk >> 9, m = blk & (MSEG - 1);
    double xa = X[(size_t)b * NPADC + (size_t)m * LSEG + lane];
    double c = (lane == 0) ? 1.0 : 0.0;
#pragma unroll
    for (int j = 0; j < LSEG; ++j) {
        double xj = readlane_d(xa, j);
        double up = dpp_shr1_d(c);                   // lane0 -> 0
        c = fma(xj, up, c);
    }
    if (lane < KP) Bp[(size_t)blk * KP + lane] = c;
}

// ---- kernel 3a: suffix-inclusive within group + group polys (4 groups / block)
__global__ void k_group_partial(const double* __restrict__ Bp,
                                double* __restrict__ sfxI, double* __restrict__ gpoly) {
    int lane = threadIdx.x & 63;
    int blk = blockIdx.x * 4 + (threadIdx.x >> 6);   // b*NG + g
    int b = blk / NG, g = blk % NG;
    double run = (lane == 0) ? 1.0 : 0.0;
    for (int i = GSZ - 1; i >= 0; --i) {
        int m = g * GSZ + i;
        double bp = (lane < KP) ? Bp[((size_t)b * MSEG + m) * KP + lane] : 0.0;
        run = conv33(bp, run);
        if (lane < KP) sfxI[((size_t)b * MSEG + m) * KP + lane] = run;
    }
    if (lane < KP) gpoly[(size_t)blk * KP + lane] = run;
}

// ---- kernel 3b: suffix scan over group polys (exclusive carries)
__global__ void k_group_scan(const double* __restrict__ gpoly, double* __restrict__ gcarry) {
    int lane = threadIdx.x;
    int b = blockIdx.x;
    double run = (lane == 0) ? 1.0 : 0.0;
    for (int g = NG - 1; g >= 0; --g) {
        if (lane < KP) gcarry[((size_t)b * NG + g) * KP + lane] = run;
        double gp = (lane < KP) ? gpoly[((size_t)b * NG + g) * KP + lane] : 0.0;
        run = conv33(gp, run);
    }
}

// ---- kernel 3c: per-segment suffix checkpoints (4 segments / block)
__global__ void k_checkpoints(const double* __restrict__ sfxI, const double* __restrict__ gcarry,
                              double* __restrict__ Cc) {
    int lane = threadIdx.x & 63;
    int blk = blockIdx.x * 4 + (threadIdx.x >> 6);   // b*MSEG + m
    int b = blk >> 9, m = blk & (MSEG - 1);
    double a = (lane < KP) ? sfxI[(size_t)blk * KP + lane] : 0.0;
    double cg = (lane < KP) ? gcarry[((size_t)b * NG + m / GSZ) * KP + lane] : 0.0;
    double out = conv33(a, cg);
    if (lane < KP) Cc[((size_t)b * (MSEG + 1) + m) * KP + lane] = out;
    if (m == 0 && lane < KP)
        Cc[((size_t)b * (MSEG + 1) + MSEG) * KP + lane] = (lane == 0) ? 1.0 : 0.0;
}

// ---- kernel 4: backward sfx sweep fused with sampling (4 segments / block)
__global__ void k_backward(const double* __restrict__ X, const double* __restrict__ Cc,
                           const float* __restrict__ UT,
                           unsigned long long* __restrict__ masks, int* __restrict__ tab) {
    int lane = threadIdx.x & 63;
    int blk = blockIdx.x * 4 + (threadIdx.x >> 6);   // b*MSEG + m
    int b = blk >> 9, m = blk & (MSEG - 1);
    double xa = X[(size_t)b * NPADC + (size_t)m * LSEG + lane];
    float uf0 = UT[((size_t)0 * BCH + b) * NPADC + (size_t)m * LSEG + lane];
    float uf1 = UT[((size_t)1 * BCH + b) * NPADC + (size_t)m * LSEG + lane];
    double c = (lane < KP) ? Cc[((size_t)b * (MSEG + 1) + m + 1) * KP + lane] : 0.0;
    int S0 = lane, S1 = lane;
    unsigned long long mk0 = 0, mk1 = 0;
#pragma unroll
    for (int j = LSEG - 1; j >= 0; --j) {
        double xj = readlane_d(xa, j);
        double up = dpp_shr1_d(c);                   // sfx[j+1][lane-1], lane0 -> 0
        double rhs = xj * up;
        double cn = fma(xj, up, c);                  // sfx[j][lane]
        double ud0 = readlane_f_to_d(uf0, j);
        double ud1 = readlane_f_to_d(uf1, j);
        bool i0 = (ud0 * cn < rhs);                  // lane0: rhs==0 -> false
        bool i1 = (ud1 * cn < rhs);
        unsigned long long b0 = __ballot(i0);
        unsigned long long b1 = __ballot(i1);
        if (lane == j) { mk0 = b0; mk1 = b1; }       // SGPR->VGPR cndmask, no LDS
        int t0 = dpp_shr1_i(S0);
        int t1 = dpp_shr1_i(S1);
        if (i0) S0 = t0;
        if (i1) S1 = t1;
        c = cn;
    }
    size_t sb0 = (size_t)blk;
    size_t sb1 = (size_t)BCH * MSEG + blk;
    masks[sb0 * LSEG + lane] = mk0;
    masks[sb1 * LSEG + lane] = mk1;
    if (lane < KP) {
        tab[sb0 * KP + lane] = S0;
        tab[sb1 * KP + lane] = S1;
    }
}

// ---- kernel 5: hierarchical compose of per-segment tables -> per-segment entry states
__global__ void k_compose(const int* __restrict__ tab, int* __restrict__ rent) {
    __shared__ int tl[MSEG * KP];         // 67.6 KB
    __shared__ int gtab[16 * KP];
    __shared__ int gent[16];
    int sb = blockIdx.x;                  // s*BCH + b
    int tid = threadIdx.x;                // 1024
    const int* src = tab + (size_t)sb * MSEG * KP;
    for (int i = tid; i < MSEG * KP; i += 1024) tl[i] = src[i];
    __syncthreads();
    int w = tid >> 6, lane = tid & 63;
    int T = lane;
    for (int i = 0; i < 32; ++i) {
        int seg = w * 32 + i;
        int tv = (lane < KP) ? tl[seg * KP + lane] : 0;
        T = __shfl(tv, T, 64);
    }
    if (lane < KP) gtab[w * KP + lane] = T;
    __syncthreads();
    if (tid == 0) {
        int r = KK;
        for (int g = 0; g < 16; ++g) { gent[g] = r; r = gtab[g * KP + r]; }
    }
    __syncthreads();
    int r = gent[w];
    for (int i = 0; i < 32; ++i) {
        int seg = w * 32 + i;
        if (lane == 0) rent[(size_t)sb * MSEG + seg] = r;
        r = tl[seg * KP + r];
    }
}

// ---- kernel 6a: replay masks along realized path -> packed bitset (scalar path)
__global__ void k_replay(const unsigned long long* __restrict__ masks,
                         const int* __restrict__ rent, unsigned long long* __restrict__ bitflat) {
    int lane = threadIdx.x & 63;
    int blk = blockIdx.x * 4 + (threadIdx.x >> 6);   // sb*MSEG + m
    unsigned long long mv = masks[(size_t)blk * LSEG + lane];
    int mlo = (int)(unsigned)mv;
    int mhi = (int)(unsigned)(mv >> 32);
    int r = __builtin_amdgcn_readfirstlane(rent[blk]);
    unsigned long long sel = 0;
#pragma unroll
    for (int j = 0; j < LSEG; ++j) {
        unsigned lo = (unsigned)__builtin_amdgcn_readlane(mlo, j);
        unsigned hi = (unsigned)__builtin_amdgcn_readlane(mhi, j);
        unsigned long long mj = ((unsigned long long)hi << 32) | lo;
        int inc = (int)((mj >> r) & 1ull);
        sel |= ((unsigned long long)inc) << j;
        r -= inc;
    }
    if (lane == 0) bitflat[blk] = sel;
}

// ---- kernel 6b: coalesced symmetric mask emission from LDS bitset
__global__ void k_emit_mask(const unsigned long long* __restrict__ bitflat,
                            float* __restrict__ outMask) {
    __shared__ unsigned long long bf[MSEG];
    int sb = blockIdx.y;
    int i = blockIdx.x;
    int j = threadIdx.x;                  // 256
    bf[j] = bitflat[(size_t)sb * MSEG + j];
    bf[j + 256] = bitflat[(size_t)sb * MSEG + 256 + j];
    __syncthreads();
    float v = 0.0f;
    if (j > i) {
        int t = OFFS(i) + j - i - 1;
        v = (float)((bf[t >> 6] >> (t & 63)) & 1ull);
    } else if (j < i) {
        int t = OFFS(j) + i - j - 1;
        v = (float)((bf[t >> 6] >> (t & 63)) & 1ull);
    }
    outMask[((size_t)sb * NMAXC + i) * NMAXC + j] = v;
}

// ---- kernel 7a: flat marginals by deflation (coalesced)
__global__ void k_margflat(const double* __restrict__ X, const double* __restrict__ Cc,
                           float* __restrict__ margflat) {
    __shared__ double e[KP];
    int b = blockIdx.y;
    int t = blockIdx.x * 256 + threadIdx.x;
    if (threadIdx.x < KP) e[threadIdx.x] = Cc[(size_t)b * (MSEG + 1) * KP + threadIdx.x];
    __syncthreads();
    double x = X[(size_t)b * NPADC + t];
    double f = 1.0;
#pragma unroll
    for (int k = 1; k < KK; ++k) f = fma(-x, f, e[k]);
    margflat[(size_t)b * NPADC + t] = (float)(x * f / e[KK]);
}

// ---- kernel 7b: coalesced symmetric marginal emission
__global__ void k_emit_marg(const float* __restrict__ margflat, float* __restrict__ outMarg) {
    int b = blockIdx.y;
    int i = blockIdx.x;
    int j = threadIdx.x;                  // 256
    float v = 0.0f;
    if (j > i) v = margflat[(size_t)b * NPADC + OFFS(i) + j - i - 1];
    else if (j < i) v = margflat[(size_t)b * NPADC + OFFS(j) + i - j - 1];
    outMarg[((size_t)b * NMAXC + i) * NMAXC + j] = v;
}

extern "C" void kernel_launch(void* const* d_in, const int* in_sizes, int n_in,
                              void* d_out, int out_size, void* d_ws, size_t ws_size,
                              hipStream_t stream) {
    const float* scores = (const float*)d_in[0];
    const float* uniforms = (const float*)d_in[1];

    char* ws = (char*)d_ws;
    size_t off = 0;
    auto alloc = [&](size_t bytes) {
        void* p = ws + off;
        off += (bytes + 255) & ~(size_t)255;
        return p;
    };
    double* X      = (double*)alloc((size_t)BCH * NPADC * 8);
    float*  UT     = (float*)alloc((size_t)SS * BCH * NPADC * 4);
    double* Bp     = (double*)alloc((size_t)BCH * MSEG * KP * 8);
    double* sfxI   = (double*)alloc((size_t)BCH * MSEG * KP * 8);
    double* gpoly  = (double*)alloc((size_t)BCH * NG * KP * 8);
    double* gcarry = (double*)alloc((size_t)BCH * NG * KP * 8);
    double* Cc     = (double*)alloc((size_t)BCH * (MSEG + 1) * KP * 8);
    unsigned long long* masks = (unsigned long long*)alloc((size_t)SS * BCH * MSEG * LSEG * 8);
    int* tab       = (int*)alloc((size_t)SS * BCH * MSEG * KP * 4);
    int* rent      = (int*)alloc((size_t)SS * BCH * MSEG * 4);
    unsigned long long* bitflat = (unsigned long long*)alloc((size_t)SS * BCH * MSEG * 8);
    float* margflat = (float*)alloc((size_t)BCH * NPADC * 4);
    if (off > ws_size) return;            // ~56 MB

    k_exp_row<<<dim3(NMAXC, BCH), 256, 0, stream>>>(scores, X);
    k_padX<<<16, 256, 0, stream>>>(X);
    k_utrans<<<dim3(NPADC / 64, SS), 256, 0, stream>>>(uniforms, UT);
    k_block_poly<<<BCH * MSEG / 4, 256, 0, stream>>>(X, Bp);
    k_group_partial<<<BCH * NG / 4, 256, 0, stream>>>(Bp, sfxI, gpoly);
    k_group_scan<<<BCH, 64, 0, stream>>>(gpoly, gcarry);
    k_checkpoints<<<BCH * MSEG / 4, 256, 0, stream>>>(sfxI, gcarry, Cc);
    k_backward<<<BCH * MSEG / 4, 256, 0, stream>>>(X, Cc, UT, masks, tab);
    k_compose<<<SS * BCH, 1024, 0, stream>>>(tab, rent);
    k_replay<<<SS * BCH * MSEG / 4, 256, 0, stream>>>(masks, rent, bitflat);
    k_emit_mask<<<dim3(NMAXC, SS * BCH), 256, 0, stream>>>(bitflat, (float*)d_out);
    k_margflat<<<dim3(NPADC / 256, BCH), 256, 0, stream>>>(X, Cc, margflat);
    k_emit_marg<<<dim3(NMAXC, BCH), 256, 0, stream>>>(
        margflat, (float*)d_out + (size_t)SS * BCH * NMAXC * NMAXC);
}